// Round 2
// baseline (491.761 us; speedup 1.0000x reference)
//
#include <hip/hip_runtime.h>
#include <math.h>

// ---------------------------------------------------------------------------
// Multi-head self-attention, bf16 MFMA pipeline. R11:
//  - attn: REVERT R10's KVBLK=32 (regressed 112->263 µs: FETCH 42->275 MB,
//    L2 reuse across qg-blocks sharing K/V collapsed; half the compute per
//    barrier could no longer cover the vmcnt(0) drain). Back to R9's
//    KVBLK=64 structure.
//  - attn: keep T5 s_setprio(1) around QK and PV MFMA clusters (m191:
//    +4-7% on multi-block attn; 4 independent blocks/CU here).
//  - GEMMs/prep unchanged from R9.
// ---------------------------------------------------------------------------

typedef __bf16 bf16x8 __attribute__((ext_vector_type(8)));
typedef float f32x4 __attribute__((ext_vector_type(4)));

#define EMBED 1024
#define NHEAD 16
#define BATCH 4
#define SEQ 2048
#define M_TOT 8192
#define QKV_N 3072
#define QSCALE 0.18033688011112042f  // 0.125 * log2(e)

__device__ __forceinline__ ushort f2bf(float f) {
  union { float f; unsigned u; } x; x.f = f;
  unsigned r = x.u + 0x7FFFu + ((x.u >> 16) & 1u);  // RNE
  return (ushort)(r >> 16);
}

// packed f32x2 -> bf16x2 (low = a, high = b)
__device__ __forceinline__ uint cvt2bf(float a, float b) {
#if __has_builtin(__builtin_amdgcn_cvt_pk_bf16_f32)
  typedef __bf16 bf16x2 __attribute__((ext_vector_type(2)));
  union { bf16x2 v; uint u; } c;
  c.v = __builtin_amdgcn_cvt_pk_bf16_f32(a, b);
  return c.u;
#else
  return (uint)f2bf(a) | ((uint)f2bf(b) << 16);
#endif
}

// raw v_exp_f32
__device__ __forceinline__ float fexp2(float x) {
#if __has_builtin(__builtin_amdgcn_exp2f)
  return __builtin_amdgcn_exp2f(x);
#else
  return exp2f(x);
#endif
}

__device__ __forceinline__ f32x4 mfma16(bf16x8 a, bf16x8 b, f32x4 c) {
  return __builtin_amdgcn_mfma_f32_16x16x32_bf16(a, b, c, 0, 0, 0);
}

// async global->LDS, 16B per lane; LDS base wave-uniform, lane i -> base+i*16
__device__ __forceinline__ void gl2lds16(const void* g, void* l) {
  __builtin_amdgcn_global_load_lds(
      (const __attribute__((address_space(1))) unsigned int*)g,
      (__attribute__((address_space(3))) unsigned int*)l, 16, 0, 0);
}

// --------------------------------------------------------------------------
// Fused prep: [0,8192) x->bf16 cast; [8192,8960) Wqkv transpose;
// [8960,9216) Wproj transpose. Branches are block-uniform.
// --------------------------------------------------------------------------
__global__ __launch_bounds__(256) void prep_kernel(
    const float* __restrict__ x, ushort* __restrict__ xb,
    const float* __restrict__ Wqkv, ushort* __restrict__ Wqkv_t,
    const float* __restrict__ Wproj, ushort* __restrict__ Wproj_t) {
  __shared__ float tile[64][65];
  const int bid = blockIdx.x;
  const int t = threadIdx.x;
  if (bid < 8192) {
    int i = (bid * 256 + t) * 4;
    float4 v = *reinterpret_cast<const float4*>(&x[i]);
    uint2 w = {cvt2bf(v.x, v.y), cvt2bf(v.z, v.w)};
    *reinterpret_cast<uint2*>(&xb[i]) = w;
    return;
  }
  const float* in;
  ushort* out;
  int Kd = 1024, Nd, n0, k0;
  if (bid < 8960) {
    int b2 = bid - 8192;               // 48 x 16 blocks
    in = Wqkv; out = Wqkv_t; Nd = 3072;
    n0 = (b2 % 48) * 64; k0 = (b2 / 48) * 64;
  } else {
    int b2 = bid - 8960;               // 16 x 16 blocks
    in = Wproj; out = Wproj_t; Nd = 1024;
    n0 = (b2 % 16) * 64; k0 = (b2 / 16) * 64;
  }
#pragma unroll
  for (int i = 0; i < 16; ++i) {
    int e = t + 256 * i;
    int kr = e >> 6, nc = e & 63;
    tile[kr][nc] = in[(size_t)(k0 + kr) * Nd + n0 + nc];
  }
  __syncthreads();
#pragma unroll
  for (int i = 0; i < 16; ++i) {
    int e = t + 256 * i;
    int nr = e >> 6, kc = e & 63;
    out[(size_t)(n0 + nr) * Kd + k0 + kc] = f2bf(tile[kc][nr]);
  }
}

// --------------------------------------------------------------------------
// Pure-bf16 GEMM: 128x128 tile, BK=64 (32 MFMA/barrier/wave), global_load_lds
// staging with XOR source-column swizzle (8 chunks/row, 3-bit XOR).
// mode 0: fp32 out = acc + bias (proj).   mode 1: QKV split epilogue.
// --------------------------------------------------------------------------
__global__ __launch_bounds__(256) void gemm_bf16(
    const ushort* __restrict__ A, const ushort* __restrict__ Bt,
    const float* __restrict__ bias, void* __restrict__ Cout,
    ushort* __restrict__ vtgout, int M, int N, int K, int mode) {
  __shared__ ushort As[128 * 64];
  __shared__ ushort Bs[128 * 64];
  const int t = threadIdx.x;
  const int wave = t >> 6, lane = t & 63;
  const int lane15 = lane & 15, quad = lane >> 4;
  const int m0 = blockIdx.y * 128, n0 = blockIdx.x * 128;
  const int wm = (wave >> 1) * 64, wn = (wave & 1) * 64;

  // staging: chunk c = (j*4+wave)*64+lane; row=c>>3; LDS linear at c*8
  // ushorts; source column carries the XOR: ((c&7)^(row&7))*8.
  int srow[4], scol[4], sdst[4];
#pragma unroll
  for (int j = 0; j < 4; ++j) {
    int c = (j * 4 + wave) * 64 + lane;
    int row = c >> 3;
    scol[j] = ((c & 7) ^ (row & 7)) * 8;
    srow[j] = row;
    sdst[j] = (j * 4 + wave) * 512;
  }
  const int sw = lane15 & 7;  // frag-read XOR (row = ..+lane15, &7)

  f32x4 acc[4][4] = {};

  for (int k0 = 0; k0 < K; k0 += 64) {
#pragma unroll
    for (int j = 0; j < 4; ++j) {
      gl2lds16(&A[(size_t)(m0 + srow[j]) * K + k0 + scol[j]], &As[sdst[j]]);
      gl2lds16(&Bt[(size_t)(n0 + srow[j]) * K + k0 + scol[j]], &Bs[sdst[j]]);
    }
    __syncthreads();

#pragma unroll
    for (int kk = 0; kk < 2; ++kk) {
      bf16x8 af[4], bfr[4];
#pragma unroll
      for (int ms = 0; ms < 4; ++ms)
        af[ms] = *reinterpret_cast<const bf16x8*>(
            &As[(wm + ms * 16 + lane15) * 64 + (((kk * 4 + quad) ^ sw) * 8)]);
#pragma unroll
      for (int ns = 0; ns < 4; ++ns)
        bfr[ns] = *reinterpret_cast<const bf16x8*>(
            &Bs[(wn + ns * 16 + lane15) * 64 + (((kk * 4 + quad) ^ sw) * 8)]);
#pragma unroll
      for (int ms = 0; ms < 4; ++ms)
#pragma unroll
        for (int ns = 0; ns < 4; ++ns)
          acc[ms][ns] = mfma16(af[ms], bfr[ns], acc[ms][ns]);
    }
    __syncthreads();
  }

  if (mode == 0) {
    float* out = (float*)Cout;
#pragma unroll
    for (int ns = 0; ns < 4; ++ns) {
      int col = n0 + wn + ns * 16 + lane15;
      float bv = bias[col];
#pragma unroll
      for (int ms = 0; ms < 4; ++ms)
#pragma unroll
        for (int r = 0; r < 4; ++r) {
          int row = m0 + wm + ms * 16 + quad * 4 + r;
          out[(size_t)row * N + col] = acc[ms][ns][r] + bv;
        }
    }
  } else {
    ushort* qk = (ushort*)Cout;
#pragma unroll
    for (int ns = 0; ns < 4; ++ns) {
      int col = n0 + wn + ns * 16 + lane15;
      float bv = bias[col];
      if (col < 2048) {  // block-uniform branch
        float sc = (col < 1024) ? QSCALE : 1.0f;
#pragma unroll
        for (int ms = 0; ms < 4; ++ms) {
          int row = m0 + wm + ms * 16 + quad * 4;
          uint u01 = cvt2bf((acc[ms][ns][0] + bv) * sc, (acc[ms][ns][1] + bv) * sc);
          uint u23 = cvt2bf((acc[ms][ns][2] + bv) * sc, (acc[ms][ns][3] + bv) * sc);
          qk[(size_t)(row + 0) * 2048 + col] = (ushort)u01;
          qk[(size_t)(row + 1) * 2048 + col] = (ushort)(u01 >> 16);
          qk[(size_t)(row + 2) * 2048 + col] = (ushort)u23;
          qk[(size_t)(row + 3) * 2048 + col] = (ushort)(u23 >> 16);
        }
      } else {  // V -> global V^T [b*1024 + (col-2048)][seq], 4 seq contiguous
        int dp = col - 2048;
#pragma unroll
        for (int ms = 0; ms < 4; ++ms) {
          int row = m0 + wm + ms * 16 + quad * 4;
          int b = row >> 11, seq = row & 2047;
          uint2 w = {cvt2bf(acc[ms][ns][0] + bv, acc[ms][ns][1] + bv),
                     cvt2bf(acc[ms][ns][2] + bv, acc[ms][ns][3] + bv)};
          *reinterpret_cast<uint2*>(
              &vtgout[((size_t)(b * 1024 + dp) << 11) + seq]) = w;
        }
      }
    }
  }
}

// --------------------------------------------------------------------------
// Flash attention, fixed-offset softmax, QG=2 q-tiles per block.
// Grid (bh=64, qg=16), 256 thr = 4 waves, 40960 B LDS -> 4 blocks/CU.
// --------------------------------------------------------------------------
#define QG 2  // q-tiles (of 64 rows) per block

__global__ __launch_bounds__(256, 4) void attn_kernel(
    const ushort* __restrict__ qk, const ushort* __restrict__ vtg,
    ushort* __restrict__ out) {
  __shared__ ushort Ks[2][4096];     // swizzled [key][d], double-buffered
  __shared__ ushort Vt[2][4096];     // swizzled [d][key], double-buffered
  __shared__ ushort Ps[4][16 * 64];  // per-wave [q][key], XOR-swizzled

  const int t = threadIdx.x;
  const int wave = t >> 6, lane = t & 63;
  const int lane15 = lane & 15, quad = lane >> 4;
  const int bh = blockIdx.x, qg = blockIdx.y;
  const int b = bh >> 4, h = bh & 15;
  const size_t boff = (size_t)b * SEQ * 2048;

  int sdst[2];
  const ushort* kptr[2];
  const ushort* vptr[2];
#pragma unroll
  for (int j = 0; j < 2; ++j) {
    int lg = (j * 4 + wave) * 64 + lane;
    int row = lg >> 3;
    int col = ((lg & 7) ^ (row & 7)) * 8;
    sdst[j] = (j * 4 + wave) * 512;
    kptr[j] = qk + boff + (size_t)row * 2048 + 1024 + h * 64 + col;
    vptr[j] = vtg + ((size_t)(b * 1024 + h * 64 + row) << 11) + col;
  }

  // Q fragments for QG q-tiles (B-operand for S^T = K*Q^T); pre-scaled
  bf16x8 qf[QG][2];
#pragma unroll
  for (int g = 0; g < QG; ++g) {
    size_t qoff = boff +
        (size_t)(qg * (QG * 64) + g * 64 + wave * 16 + lane15) * 2048 + h * 64;
    qf[g][0] = *reinterpret_cast<const bf16x8*>(&qk[qoff + quad * 8]);
    qf[g][1] = *reinterpret_cast<const bf16x8*>(&qk[qoff + 32 + quad * 8]);
  }

  bf16x8 ones;
#pragma unroll
  for (int j = 0; j < 8; ++j) ones[j] = (__bf16)1.0f;

  f32x4 O[QG][4] = {};  // rows q=quad*4+r, cols d=dsub*16+lane15
  f32x4 lacc[QG] = {};  // row-sums of P, broadcast over cols
  const int sw = lane15 & 7;
  ushort* ps = Ps[wave];

  // prologue: stage kt=0 into buffer 0
#pragma unroll
  for (int j = 0; j < 2; ++j) {
    gl2lds16(kptr[j], &Ks[0][sdst[j]]);
    gl2lds16(vptr[j], &Vt[0][sdst[j]]);
  }
  __syncthreads();

  for (int kt = 0; kt < SEQ / 64; ++kt) {
    const int cur = kt & 1, nxt = cur ^ 1;
    if (kt < SEQ / 64 - 1) {
#pragma unroll
      for (int j = 0; j < 2; ++j) {
        gl2lds16(kptr[j] + (size_t)(kt + 1) * 64 * 2048, &Ks[nxt][sdst[j]]);
        gl2lds16(vptr[j] + (kt + 1) * 64, &Vt[nxt][sdst[j]]);
      }
    }

    // hoisted K and V fragment reads, shared by the QG q-tiles
    bf16x8 kf[4][2], vf[2][4];
#pragma unroll
    for (int nsub = 0; nsub < 4; ++nsub) {
      const int kr = (nsub * 16 + lane15) * 64;
      kf[nsub][0] = *reinterpret_cast<const bf16x8*>(
          &Ks[cur][kr + ((quad ^ sw) * 8)]);
      kf[nsub][1] = *reinterpret_cast<const bf16x8*>(
          &Ks[cur][kr + (((quad + 4) ^ sw) * 8)]);
    }
#pragma unroll
    for (int kk = 0; kk < 2; ++kk)
#pragma unroll
      for (int dsub = 0; dsub < 4; ++dsub) {
        int d = dsub * 16 + lane15;
        vf[kk][dsub] = *reinterpret_cast<const bf16x8*>(
            &Vt[cur][d * 64 + (((kk * 4 + quad) ^ sw) * 8)]);
      }

#pragma unroll
    for (int g = 0; g < QG; ++g) {
      // S^T = K Q^T - 32 (fixed softmax offset in acc init)
      f32x4 st[4];
      __builtin_amdgcn_s_setprio(1);
#pragma unroll
      for (int nsub = 0; nsub < 4; ++nsub) {
        f32x4 a = {-32.0f, -32.0f, -32.0f, -32.0f};
        a = mfma16(kf[nsub][0], qf[g][0], a);
        a = mfma16(kf[nsub][1], qf[g][1], a);
        st[nsub] = a;
      }
      __builtin_amdgcn_s_setprio(0);
      // p = exp2(st) -> bf16 -> Ps row q=lane15; phys 16B block =
      // (2*nsub + (quad>>1)) ^ sw, half-block offset (quad&1)*4.
#pragma unroll
      for (int nsub = 0; nsub < 4; ++nsub) {
        uint2 w = {cvt2bf(fexp2(st[nsub][0]), fexp2(st[nsub][1])),
                   cvt2bf(fexp2(st[nsub][2]), fexp2(st[nsub][3]))};
        *reinterpret_cast<uint2*>(
            &ps[lane15 * 64 + (((2 * nsub + (quad >> 1)) ^ sw) << 3) +
                ((quad & 1) << 2)]) = w;
      }
      // O += P V ; lacc += P * ones. pf block = (kk*4+quad) ^ sw.
#pragma unroll
      for (int kk = 0; kk < 2; ++kk) {
        bf16x8 pf = *reinterpret_cast<const bf16x8*>(
            &ps[lane15 * 64 + (((kk * 4 + quad) ^ sw) << 3)]);
        __builtin_amdgcn_s_setprio(1);
#pragma unroll
        for (int dsub = 0; dsub < 4; ++dsub)
          O[g][dsub] = mfma16(pf, vf[kk][dsub], O[g][dsub]);
        lacc[g] = mfma16(pf, ones, lacc[g]);
        __builtin_amdgcn_s_setprio(0);
      }
    }
    __syncthreads();  // guards buffer swap; prefetch had a full kt to land
  }

  // Epilogue: normalize by l, store bf16
#pragma unroll
  for (int g = 0; g < QG; ++g)
#pragma unroll
    for (int r = 0; r < 4; ++r) {
      float linv = __builtin_amdgcn_rcpf(lacc[g][r]);
      size_t rowoff =
          (size_t)(b * SEQ + qg * (QG * 64) + g * 64 + wave * 16 + quad * 4 +
                   r) * EMBED + h * 64;
      uint u01 = cvt2bf(O[g][0][r] * linv, O[g][1][r] * linv);
      uint u23 = cvt2bf(O[g][2][r] * linv, O[g][3][r] * linv);
      out[rowoff + 0 * 16 + lane15] = (ushort)u01;
      out[rowoff + 1 * 16 + lane15] = (ushort)(u01 >> 16);
      out[rowoff + 2 * 16 + lane15] = (ushort)u23;
      out[rowoff + 3 * 16 + lane15] = (ushort)(u23 >> 16);
    }
}

// --------------------------------------------------------------------------
extern "C" void kernel_launch(void* const* d_in, const int* in_sizes, int n_in,
                              void* d_out, int out_size, void* d_ws,
                              size_t ws_size, hipStream_t stream) {
  const float* x = (const float*)d_in[0];
  const float* Wqkv = (const float*)d_in[1];
  const float* bqkv = (const float*)d_in[2];
  const float* Wproj = (const float*)d_in[3];
  const float* bproj = (const float*)d_in[4];
  float* out = (float*)d_out;

  char* ws = (char*)d_ws;
  // ws layout (75.5 MB):
  //   Wqkv_t  bf16 [3072][1024]        6 MB   @ 0
  //   Wproj_t bf16 [1024][1024]        2 MB   @ 6291456
  //   qk      bf16 [8192][2048]       32 MB   @ 8388608
  //   vtg     bf16 [4][16][64][2048]  16 MB   @ 41943040
  //   xb / attnout (aliased) bf16     16 MB   @ 58720256
  ushort* Wqkv_t = (ushort*)ws;
  ushort* Wproj_t = (ushort*)(ws + 6291456);
  ushort* qk = (ushort*)(ws + 8388608);
  ushort* vtg = (ushort*)(ws + 41943040);
  ushort* xb = (ushort*)(ws + 58720256);
  ushort* attnout = (ushort*)(ws + 58720256);  // alias: xb dead after QKV GEMM

  prep_kernel<<<8192 + 768 + 256, 256, 0, stream>>>(
      x, xb, Wqkv, Wqkv_t, Wproj, Wproj_t);
  gemm_bf16<<<dim3(QKV_N / 128, M_TOT / 128), 256, 0, stream>>>(
      xb, Wqkv_t, bqkv, qk, vtg, M_TOT, QKV_N, EMBED, 1);
  attn_kernel<<<dim3(NHEAD * BATCH, SEQ / (QG * 64)), 256, 0, stream>>>(
      qk, vtg, attnout);
  gemm_bf16<<<dim3(EMBED / 128, M_TOT / 128), 256, 0, stream>>>(
      attnout, Wproj_t, bproj, out, nullptr, M_TOT, EMBED, EMBED, 0);
}

// Round 3
// 293.798 us; speedup vs baseline: 1.6738x; 1.6738x over previous
//
#include <hip/hip_runtime.h>
#include <math.h>

// ---------------------------------------------------------------------------
// Multi-head self-attention, bf16 MFMA pipeline. R12:
//  - EXACT revert to the verified 291.2 µs R9 source. R10 (KVBLK=32) and
//    R11 (R9 + s_setprio) both regressed; R11's counter signature
//    (WRITE_SIZE 40->699 MB, FETCH 42->639 MB, FETCH~WRITE) is scratch-
//    spill thrash: setprio perturbed regalloc past the AGPR-absorbable
//    register cliff (~20 regs spilled/reloaded per kt iteration). No
//    setprio anywhere; code below is byte-identical to the R9 kernel.
// ---------------------------------------------------------------------------

typedef __bf16 bf16x8 __attribute__((ext_vector_type(8)));
typedef float f32x4 __attribute__((ext_vector_type(4)));

#define EMBED 1024
#define NHEAD 16
#define BATCH 4
#define SEQ 2048
#define M_TOT 8192
#define QKV_N 3072
#define QSCALE 0.18033688011112042f  // 0.125 * log2(e)

__device__ __forceinline__ ushort f2bf(float f) {
  union { float f; unsigned u; } x; x.f = f;
  unsigned r = x.u + 0x7FFFu + ((x.u >> 16) & 1u);  // RNE
  return (ushort)(r >> 16);
}

// packed f32x2 -> bf16x2 (low = a, high = b)
__device__ __forceinline__ uint cvt2bf(float a, float b) {
#if __has_builtin(__builtin_amdgcn_cvt_pk_bf16_f32)
  typedef __bf16 bf16x2 __attribute__((ext_vector_type(2)));
  union { bf16x2 v; uint u; } c;
  c.v = __builtin_amdgcn_cvt_pk_bf16_f32(a, b);
  return c.u;
#else
  return (uint)f2bf(a) | ((uint)f2bf(b) << 16);
#endif
}

// raw v_exp_f32
__device__ __forceinline__ float fexp2(float x) {
#if __has_builtin(__builtin_amdgcn_exp2f)
  return __builtin_amdgcn_exp2f(x);
#else
  return exp2f(x);
#endif
}

__device__ __forceinline__ f32x4 mfma16(bf16x8 a, bf16x8 b, f32x4 c) {
  return __builtin_amdgcn_mfma_f32_16x16x32_bf16(a, b, c, 0, 0, 0);
}

// async global->LDS, 16B per lane; LDS base wave-uniform, lane i -> base+i*16
__device__ __forceinline__ void gl2lds16(const void* g, void* l) {
  __builtin_amdgcn_global_load_lds(
      (const __attribute__((address_space(1))) unsigned int*)g,
      (__attribute__((address_space(3))) unsigned int*)l, 16, 0, 0);
}

// --------------------------------------------------------------------------
// Fused prep: [0,8192) x->bf16 cast; [8192,8960) Wqkv transpose;
// [8960,9216) Wproj transpose. Branches are block-uniform.
// --------------------------------------------------------------------------
__global__ __launch_bounds__(256) void prep_kernel(
    const float* __restrict__ x, ushort* __restrict__ xb,
    const float* __restrict__ Wqkv, ushort* __restrict__ Wqkv_t,
    const float* __restrict__ Wproj, ushort* __restrict__ Wproj_t) {
  __shared__ float tile[64][65];
  const int bid = blockIdx.x;
  const int t = threadIdx.x;
  if (bid < 8192) {
    int i = (bid * 256 + t) * 4;
    float4 v = *reinterpret_cast<const float4*>(&x[i]);
    uint2 w = {cvt2bf(v.x, v.y), cvt2bf(v.z, v.w)};
    *reinterpret_cast<uint2*>(&xb[i]) = w;
    return;
  }
  const float* in;
  ushort* out;
  int Kd = 1024, Nd, n0, k0;
  if (bid < 8960) {
    int b2 = bid - 8192;               // 48 x 16 blocks
    in = Wqkv; out = Wqkv_t; Nd = 3072;
    n0 = (b2 % 48) * 64; k0 = (b2 / 48) * 64;
  } else {
    int b2 = bid - 8960;               // 16 x 16 blocks
    in = Wproj; out = Wproj_t; Nd = 1024;
    n0 = (b2 % 16) * 64; k0 = (b2 / 16) * 64;
  }
#pragma unroll
  for (int i = 0; i < 16; ++i) {
    int e = t + 256 * i;
    int kr = e >> 6, nc = e & 63;
    tile[kr][nc] = in[(size_t)(k0 + kr) * Nd + n0 + nc];
  }
  __syncthreads();
#pragma unroll
  for (int i = 0; i < 16; ++i) {
    int e = t + 256 * i;
    int nr = e >> 6, kc = e & 63;
    out[(size_t)(n0 + nr) * Kd + k0 + kc] = f2bf(tile[kc][nr]);
  }
}

// --------------------------------------------------------------------------
// Pure-bf16 GEMM: 128x128 tile, BK=64 (32 MFMA/barrier/wave), global_load_lds
// staging with XOR source-column swizzle (8 chunks/row, 3-bit XOR).
// mode 0: fp32 out = acc + bias (proj).   mode 1: QKV split epilogue.
// --------------------------------------------------------------------------
__global__ __launch_bounds__(256) void gemm_bf16(
    const ushort* __restrict__ A, const ushort* __restrict__ Bt,
    const float* __restrict__ bias, void* __restrict__ Cout,
    ushort* __restrict__ vtgout, int M, int N, int K, int mode) {
  __shared__ ushort As[128 * 64];
  __shared__ ushort Bs[128 * 64];
  const int t = threadIdx.x;
  const int wave = t >> 6, lane = t & 63;
  const int lane15 = lane & 15, quad = lane >> 4;
  const int m0 = blockIdx.y * 128, n0 = blockIdx.x * 128;
  const int wm = (wave >> 1) * 64, wn = (wave & 1) * 64;

  // staging: chunk c = (j*4+wave)*64+lane; row=c>>3; LDS linear at c*8
  // ushorts; source column carries the XOR: ((c&7)^(row&7))*8.
  int srow[4], scol[4], sdst[4];
#pragma unroll
  for (int j = 0; j < 4; ++j) {
    int c = (j * 4 + wave) * 64 + lane;
    int row = c >> 3;
    scol[j] = ((c & 7) ^ (row & 7)) * 8;
    srow[j] = row;
    sdst[j] = (j * 4 + wave) * 512;
  }
  const int sw = lane15 & 7;  // frag-read XOR (row = ..+lane15, &7)

  f32x4 acc[4][4] = {};

  for (int k0 = 0; k0 < K; k0 += 64) {
#pragma unroll
    for (int j = 0; j < 4; ++j) {
      gl2lds16(&A[(size_t)(m0 + srow[j]) * K + k0 + scol[j]], &As[sdst[j]]);
      gl2lds16(&Bt[(size_t)(n0 + srow[j]) * K + k0 + scol[j]], &Bs[sdst[j]]);
    }
    __syncthreads();

#pragma unroll
    for (int kk = 0; kk < 2; ++kk) {
      bf16x8 af[4], bfr[4];
#pragma unroll
      for (int ms = 0; ms < 4; ++ms)
        af[ms] = *reinterpret_cast<const bf16x8*>(
            &As[(wm + ms * 16 + lane15) * 64 + (((kk * 4 + quad) ^ sw) * 8)]);
#pragma unroll
      for (int ns = 0; ns < 4; ++ns)
        bfr[ns] = *reinterpret_cast<const bf16x8*>(
            &Bs[(wn + ns * 16 + lane15) * 64 + (((kk * 4 + quad) ^ sw) * 8)]);
#pragma unroll
      for (int ms = 0; ms < 4; ++ms)
#pragma unroll
        for (int ns = 0; ns < 4; ++ns)
          acc[ms][ns] = mfma16(af[ms], bfr[ns], acc[ms][ns]);
    }
    __syncthreads();
  }

  if (mode == 0) {
    float* out = (float*)Cout;
#pragma unroll
    for (int ns = 0; ns < 4; ++ns) {
      int col = n0 + wn + ns * 16 + lane15;
      float bv = bias[col];
#pragma unroll
      for (int ms = 0; ms < 4; ++ms)
#pragma unroll
        for (int r = 0; r < 4; ++r) {
          int row = m0 + wm + ms * 16 + quad * 4 + r;
          out[(size_t)row * N + col] = acc[ms][ns][r] + bv;
        }
    }
  } else {
    ushort* qk = (ushort*)Cout;
#pragma unroll
    for (int ns = 0; ns < 4; ++ns) {
      int col = n0 + wn + ns * 16 + lane15;
      float bv = bias[col];
      if (col < 2048) {  // block-uniform branch
        float sc = (col < 1024) ? QSCALE : 1.0f;
#pragma unroll
        for (int ms = 0; ms < 4; ++ms) {
          int row = m0 + wm + ms * 16 + quad * 4;
          uint u01 = cvt2bf((acc[ms][ns][0] + bv) * sc, (acc[ms][ns][1] + bv) * sc);
          uint u23 = cvt2bf((acc[ms][ns][2] + bv) * sc, (acc[ms][ns][3] + bv) * sc);
          qk[(size_t)(row + 0) * 2048 + col] = (ushort)u01;
          qk[(size_t)(row + 1) * 2048 + col] = (ushort)(u01 >> 16);
          qk[(size_t)(row + 2) * 2048 + col] = (ushort)u23;
          qk[(size_t)(row + 3) * 2048 + col] = (ushort)(u23 >> 16);
        }
      } else {  // V -> global V^T [b*1024 + (col-2048)][seq], 4 seq contiguous
        int dp = col - 2048;
#pragma unroll
        for (int ms = 0; ms < 4; ++ms) {
          int row = m0 + wm + ms * 16 + quad * 4;
          int b = row >> 11, seq = row & 2047;
          uint2 w = {cvt2bf(acc[ms][ns][0] + bv, acc[ms][ns][1] + bv),
                     cvt2bf(acc[ms][ns][2] + bv, acc[ms][ns][3] + bv)};
          *reinterpret_cast<uint2*>(
              &vtgout[((size_t)(b * 1024 + dp) << 11) + seq]) = w;
        }
      }
    }
  }
}

// --------------------------------------------------------------------------
// Flash attention, fixed-offset softmax, QG=2 q-tiles per block.
// Grid (bh=64, qg=16), 256 thr = 4 waves, 40960 B LDS -> 4 blocks/CU.
// --------------------------------------------------------------------------
#define QG 2  // q-tiles (of 64 rows) per block

__global__ __launch_bounds__(256, 4) void attn_kernel(
    const ushort* __restrict__ qk, const ushort* __restrict__ vtg,
    ushort* __restrict__ out) {
  __shared__ ushort Ks[2][4096];     // swizzled [key][d], double-buffered
  __shared__ ushort Vt[2][4096];     // swizzled [d][key], double-buffered
  __shared__ ushort Ps[4][16 * 64];  // per-wave [q][key], XOR-swizzled

  const int t = threadIdx.x;
  const int wave = t >> 6, lane = t & 63;
  const int lane15 = lane & 15, quad = lane >> 4;
  const int bh = blockIdx.x, qg = blockIdx.y;
  const int b = bh >> 4, h = bh & 15;
  const size_t boff = (size_t)b * SEQ * 2048;

  int sdst[2];
  const ushort* kptr[2];
  const ushort* vptr[2];
#pragma unroll
  for (int j = 0; j < 2; ++j) {
    int lg = (j * 4 + wave) * 64 + lane;
    int row = lg >> 3;
    int col = ((lg & 7) ^ (row & 7)) * 8;
    sdst[j] = (j * 4 + wave) * 512;
    kptr[j] = qk + boff + (size_t)row * 2048 + 1024 + h * 64 + col;
    vptr[j] = vtg + ((size_t)(b * 1024 + h * 64 + row) << 11) + col;
  }

  // Q fragments for QG q-tiles (B-operand for S^T = K*Q^T); pre-scaled
  bf16x8 qf[QG][2];
#pragma unroll
  for (int g = 0; g < QG; ++g) {
    size_t qoff = boff +
        (size_t)(qg * (QG * 64) + g * 64 + wave * 16 + lane15) * 2048 + h * 64;
    qf[g][0] = *reinterpret_cast<const bf16x8*>(&qk[qoff + quad * 8]);
    qf[g][1] = *reinterpret_cast<const bf16x8*>(&qk[qoff + 32 + quad * 8]);
  }

  bf16x8 ones;
#pragma unroll
  for (int j = 0; j < 8; ++j) ones[j] = (__bf16)1.0f;

  f32x4 O[QG][4] = {};  // rows q=quad*4+r, cols d=dsub*16+lane15
  f32x4 lacc[QG] = {};  // row-sums of P, broadcast over cols
  const int sw = lane15 & 7;
  ushort* ps = Ps[wave];

  // prologue: stage kt=0 into buffer 0
#pragma unroll
  for (int j = 0; j < 2; ++j) {
    gl2lds16(kptr[j], &Ks[0][sdst[j]]);
    gl2lds16(vptr[j], &Vt[0][sdst[j]]);
  }
  __syncthreads();

  for (int kt = 0; kt < SEQ / 64; ++kt) {
    const int cur = kt & 1, nxt = cur ^ 1;
    if (kt < SEQ / 64 - 1) {
#pragma unroll
      for (int j = 0; j < 2; ++j) {
        gl2lds16(kptr[j] + (size_t)(kt + 1) * 64 * 2048, &Ks[nxt][sdst[j]]);
        gl2lds16(vptr[j] + (kt + 1) * 64, &Vt[nxt][sdst[j]]);
      }
    }

    // hoisted K and V fragment reads, shared by the QG q-tiles
    bf16x8 kf[4][2], vf[2][4];
#pragma unroll
    for (int nsub = 0; nsub < 4; ++nsub) {
      const int kr = (nsub * 16 + lane15) * 64;
      kf[nsub][0] = *reinterpret_cast<const bf16x8*>(
          &Ks[cur][kr + ((quad ^ sw) * 8)]);
      kf[nsub][1] = *reinterpret_cast<const bf16x8*>(
          &Ks[cur][kr + (((quad + 4) ^ sw) * 8)]);
    }
#pragma unroll
    for (int kk = 0; kk < 2; ++kk)
#pragma unroll
      for (int dsub = 0; dsub < 4; ++dsub) {
        int d = dsub * 16 + lane15;
        vf[kk][dsub] = *reinterpret_cast<const bf16x8*>(
            &Vt[cur][d * 64 + (((kk * 4 + quad) ^ sw) * 8)]);
      }

#pragma unroll
    for (int g = 0; g < QG; ++g) {
      // S^T = K Q^T - 32 (fixed softmax offset in acc init)
      f32x4 st[4];
#pragma unroll
      for (int nsub = 0; nsub < 4; ++nsub) {
        f32x4 a = {-32.0f, -32.0f, -32.0f, -32.0f};
        a = mfma16(kf[nsub][0], qf[g][0], a);
        a = mfma16(kf[nsub][1], qf[g][1], a);
        st[nsub] = a;
      }
      // p = exp2(st) -> bf16 -> Ps row q=lane15; phys 16B block =
      // (2*nsub + (quad>>1)) ^ sw, half-block offset (quad&1)*4.
#pragma unroll
      for (int nsub = 0; nsub < 4; ++nsub) {
        uint2 w = {cvt2bf(fexp2(st[nsub][0]), fexp2(st[nsub][1])),
                   cvt2bf(fexp2(st[nsub][2]), fexp2(st[nsub][3]))};
        *reinterpret_cast<uint2*>(
            &ps[lane15 * 64 + (((2 * nsub + (quad >> 1)) ^ sw) << 3) +
                ((quad & 1) << 2)]) = w;
      }
      // O += P V ; lacc += P * ones. pf block = (kk*4+quad) ^ sw.
#pragma unroll
      for (int kk = 0; kk < 2; ++kk) {
        bf16x8 pf = *reinterpret_cast<const bf16x8*>(
            &ps[lane15 * 64 + (((kk * 4 + quad) ^ sw) << 3)]);
#pragma unroll
        for (int dsub = 0; dsub < 4; ++dsub)
          O[g][dsub] = mfma16(pf, vf[kk][dsub], O[g][dsub]);
        lacc[g] = mfma16(pf, ones, lacc[g]);
      }
    }
    __syncthreads();  // guards buffer swap; prefetch had a full kt to land
  }

  // Epilogue: normalize by l, store bf16
#pragma unroll
  for (int g = 0; g < QG; ++g)
#pragma unroll
    for (int r = 0; r < 4; ++r) {
      float linv = __builtin_amdgcn_rcpf(lacc[g][r]);
      size_t rowoff =
          (size_t)(b * SEQ + qg * (QG * 64) + g * 64 + wave * 16 + quad * 4 +
                   r) * EMBED + h * 64;
      uint u01 = cvt2bf(O[g][0][r] * linv, O[g][1][r] * linv);
      uint u23 = cvt2bf(O[g][2][r] * linv, O[g][3][r] * linv);
      out[rowoff + 0 * 16 + lane15] = (ushort)u01;
      out[rowoff + 1 * 16 + lane15] = (ushort)(u01 >> 16);
      out[rowoff + 2 * 16 + lane15] = (ushort)u23;
      out[rowoff + 3 * 16 + lane15] = (ushort)(u23 >> 16);
    }
}

// --------------------------------------------------------------------------
extern "C" void kernel_launch(void* const* d_in, const int* in_sizes, int n_in,
                              void* d_out, int out_size, void* d_ws,
                              size_t ws_size, hipStream_t stream) {
  const float* x = (const float*)d_in[0];
  const float* Wqkv = (const float*)d_in[1];
  const float* bqkv = (const float*)d_in[2];
  const float* Wproj = (const float*)d_in[3];
  const float* bproj = (const float*)d_in[4];
  float* out = (float*)d_out;

  char* ws = (char*)d_ws;
  // ws layout (75.5 MB):
  //   Wqkv_t  bf16 [3072][1024]        6 MB   @ 0
  //   Wproj_t bf16 [1024][1024]        2 MB   @ 6291456
  //   qk      bf16 [8192][2048]       32 MB   @ 8388608
  //   vtg     bf16 [4][16][64][2048]  16 MB   @ 41943040
  //   xb / attnout (aliased) bf16     16 MB   @ 58720256
  ushort* Wqkv_t = (ushort*)ws;
  ushort* Wproj_t = (ushort*)(ws + 6291456);
  ushort* qk = (ushort*)(ws + 8388608);
  ushort* vtg = (ushort*)(ws + 41943040);
  ushort* xb = (ushort*)(ws + 58720256);
  ushort* attnout = (ushort*)(ws + 58720256);  // alias: xb dead after QKV GEMM

  prep_kernel<<<8192 + 768 + 256, 256, 0, stream>>>(
      x, xb, Wqkv, Wqkv_t, Wproj, Wproj_t);
  gemm_bf16<<<dim3(QKV_N / 128, M_TOT / 128), 256, 0, stream>>>(
      xb, Wqkv_t, bqkv, qk, vtg, M_TOT, QKV_N, EMBED, 1);
  attn_kernel<<<dim3(NHEAD * BATCH, SEQ / (QG * 64)), 256, 0, stream>>>(
      qk, vtg, attnout);
  gemm_bf16<<<dim3(EMBED / 128, M_TOT / 128), 256, 0, stream>>>(
      attnout, Wproj_t, bproj, out, nullptr, M_TOT, EMBED, EMBED, 0);
}

// Round 4
// 276.733 us; speedup vs baseline: 1.7770x; 1.0617x over previous
//
#include <hip/hip_runtime.h>
#include <math.h>

// ---------------------------------------------------------------------------
// Multi-head self-attention, bf16 MFMA pipeline. R13:
//  - gemm_bf16: 256->512 threads (8 waves, wave grid 2Mx4N, wave-tile 64x32,
//    acc[4][2]). Same 128x128 tile / BK=64 / staging swizzle / 2-barrier
//    loop. Motive: grid packing. At 256-thr blocks, QKV's 1536 blocks over
//    1024 co-resident slots = 1.5 rounds (75% util); proj's 512 blocks over
//    1024 slots = 50% util. With 512-thr blocks capacity is 512 (or 768)
//    blocks -> QKV packs exactly (3.0 or 2.0 rounds), proj covers all CUs.
//    Per-thread regs DROP (acc 64->32 f32), no spill-cliff risk.
//  - attn/prep: byte-identical to the verified R12 (111 µs attn). R11's
//    lesson: attn sits on a regalloc cliff — do not perturb.
// ---------------------------------------------------------------------------

typedef __bf16 bf16x8 __attribute__((ext_vector_type(8)));
typedef float f32x4 __attribute__((ext_vector_type(4)));

#define EMBED 1024
#define NHEAD 16
#define BATCH 4
#define SEQ 2048
#define M_TOT 8192
#define QKV_N 3072
#define QSCALE 0.18033688011112042f  // 0.125 * log2(e)

__device__ __forceinline__ ushort f2bf(float f) {
  union { float f; unsigned u; } x; x.f = f;
  unsigned r = x.u + 0x7FFFu + ((x.u >> 16) & 1u);  // RNE
  return (ushort)(r >> 16);
}

// packed f32x2 -> bf16x2 (low = a, high = b)
__device__ __forceinline__ uint cvt2bf(float a, float b) {
#if __has_builtin(__builtin_amdgcn_cvt_pk_bf16_f32)
  typedef __bf16 bf16x2 __attribute__((ext_vector_type(2)));
  union { bf16x2 v; uint u; } c;
  c.v = __builtin_amdgcn_cvt_pk_bf16_f32(a, b);
  return c.u;
#else
  return (uint)f2bf(a) | ((uint)f2bf(b) << 16);
#endif
}

// raw v_exp_f32
__device__ __forceinline__ float fexp2(float x) {
#if __has_builtin(__builtin_amdgcn_exp2f)
  return __builtin_amdgcn_exp2f(x);
#else
  return exp2f(x);
#endif
}

__device__ __forceinline__ f32x4 mfma16(bf16x8 a, bf16x8 b, f32x4 c) {
  return __builtin_amdgcn_mfma_f32_16x16x32_bf16(a, b, c, 0, 0, 0);
}

// async global->LDS, 16B per lane; LDS base wave-uniform, lane i -> base+i*16
__device__ __forceinline__ void gl2lds16(const void* g, void* l) {
  __builtin_amdgcn_global_load_lds(
      (const __attribute__((address_space(1))) unsigned int*)g,
      (__attribute__((address_space(3))) unsigned int*)l, 16, 0, 0);
}

// --------------------------------------------------------------------------
// Fused prep: [0,8192) x->bf16 cast; [8192,8960) Wqkv transpose;
// [8960,9216) Wproj transpose. Branches are block-uniform.
// --------------------------------------------------------------------------
__global__ __launch_bounds__(256) void prep_kernel(
    const float* __restrict__ x, ushort* __restrict__ xb,
    const float* __restrict__ Wqkv, ushort* __restrict__ Wqkv_t,
    const float* __restrict__ Wproj, ushort* __restrict__ Wproj_t) {
  __shared__ float tile[64][65];
  const int bid = blockIdx.x;
  const int t = threadIdx.x;
  if (bid < 8192) {
    int i = (bid * 256 + t) * 4;
    float4 v = *reinterpret_cast<const float4*>(&x[i]);
    uint2 w = {cvt2bf(v.x, v.y), cvt2bf(v.z, v.w)};
    *reinterpret_cast<uint2*>(&xb[i]) = w;
    return;
  }
  const float* in;
  ushort* out;
  int Kd = 1024, Nd, n0, k0;
  if (bid < 8960) {
    int b2 = bid - 8192;               // 48 x 16 blocks
    in = Wqkv; out = Wqkv_t; Nd = 3072;
    n0 = (b2 % 48) * 64; k0 = (b2 / 48) * 64;
  } else {
    int b2 = bid - 8960;               // 16 x 16 blocks
    in = Wproj; out = Wproj_t; Nd = 1024;
    n0 = (b2 % 16) * 64; k0 = (b2 / 16) * 64;
  }
#pragma unroll
  for (int i = 0; i < 16; ++i) {
    int e = t + 256 * i;
    int kr = e >> 6, nc = e & 63;
    tile[kr][nc] = in[(size_t)(k0 + kr) * Nd + n0 + nc];
  }
  __syncthreads();
#pragma unroll
  for (int i = 0; i < 16; ++i) {
    int e = t + 256 * i;
    int nr = e >> 6, kc = e & 63;
    out[(size_t)(n0 + nr) * Kd + k0 + kc] = f2bf(tile[kc][nr]);
  }
}

// --------------------------------------------------------------------------
// Pure-bf16 GEMM: 128x128 tile, BK=64, 512 threads = 8 waves (2Mx4N),
// wave-tile 64x32, global_load_lds staging with XOR source-column swizzle
// (8 chunks/row, 3-bit XOR). 2 A-chunks + 2 B-chunks staged per thread.
// mode 0: fp32 out = acc + bias (proj).   mode 1: QKV split epilogue.
// --------------------------------------------------------------------------
__global__ __launch_bounds__(512, 4) void gemm_bf16(
    const ushort* __restrict__ A, const ushort* __restrict__ Bt,
    const float* __restrict__ bias, void* __restrict__ Cout,
    ushort* __restrict__ vtgout, int M, int N, int K, int mode) {
  __shared__ ushort As[128 * 64];
  __shared__ ushort Bs[128 * 64];
  const int t = threadIdx.x;
  const int wave = t >> 6, lane = t & 63;
  const int lane15 = lane & 15, quad = lane >> 4;
  const int m0 = blockIdx.y * 128, n0 = blockIdx.x * 128;
  const int wm = (wave >> 2) * 64, wn = (wave & 3) * 32;

  // staging: chunk c = (j*8+wave)*64+lane, j=0..1 -> c in [0,1024); row=c>>3;
  // LDS linear at c*8 ushorts; source column carries the XOR:
  // ((c&7)^(row&7))*8.
  int srow[2], scol[2], sdst[2];
#pragma unroll
  for (int j = 0; j < 2; ++j) {
    int c = (j * 8 + wave) * 64 + lane;
    int row = c >> 3;
    scol[j] = ((c & 7) ^ (row & 7)) * 8;
    srow[j] = row;
    sdst[j] = (j * 8 + wave) * 512;
  }
  const int sw = lane15 & 7;  // frag-read XOR (row = ..+lane15, &7)

  f32x4 acc[4][2] = {};

  for (int k0 = 0; k0 < K; k0 += 64) {
#pragma unroll
    for (int j = 0; j < 2; ++j) {
      gl2lds16(&A[(size_t)(m0 + srow[j]) * K + k0 + scol[j]], &As[sdst[j]]);
      gl2lds16(&Bt[(size_t)(n0 + srow[j]) * K + k0 + scol[j]], &Bs[sdst[j]]);
    }
    __syncthreads();

#pragma unroll
    for (int kk = 0; kk < 2; ++kk) {
      bf16x8 af[4], bfr[2];
#pragma unroll
      for (int ms = 0; ms < 4; ++ms)
        af[ms] = *reinterpret_cast<const bf16x8*>(
            &As[(wm + ms * 16 + lane15) * 64 + (((kk * 4 + quad) ^ sw) * 8)]);
#pragma unroll
      for (int ns = 0; ns < 2; ++ns)
        bfr[ns] = *reinterpret_cast<const bf16x8*>(
            &Bs[(wn + ns * 16 + lane15) * 64 + (((kk * 4 + quad) ^ sw) * 8)]);
#pragma unroll
      for (int ms = 0; ms < 4; ++ms)
#pragma unroll
        for (int ns = 0; ns < 2; ++ns)
          acc[ms][ns] = mfma16(af[ms], bfr[ns], acc[ms][ns]);
    }
    __syncthreads();
  }

  if (mode == 0) {
    float* out = (float*)Cout;
#pragma unroll
    for (int ns = 0; ns < 2; ++ns) {
      int col = n0 + wn + ns * 16 + lane15;
      float bv = bias[col];
#pragma unroll
      for (int ms = 0; ms < 4; ++ms)
#pragma unroll
        for (int r = 0; r < 4; ++r) {
          int row = m0 + wm + ms * 16 + quad * 4 + r;
          out[(size_t)row * N + col] = acc[ms][ns][r] + bv;
        }
    }
  } else {
    ushort* qk = (ushort*)Cout;
#pragma unroll
    for (int ns = 0; ns < 2; ++ns) {
      int col = n0 + wn + ns * 16 + lane15;
      float bv = bias[col];
      if (col < 2048) {  // block-uniform branch
        float sc = (col < 1024) ? QSCALE : 1.0f;
#pragma unroll
        for (int ms = 0; ms < 4; ++ms) {
          int row = m0 + wm + ms * 16 + quad * 4;
          uint u01 = cvt2bf((acc[ms][ns][0] + bv) * sc, (acc[ms][ns][1] + bv) * sc);
          uint u23 = cvt2bf((acc[ms][ns][2] + bv) * sc, (acc[ms][ns][3] + bv) * sc);
          qk[(size_t)(row + 0) * 2048 + col] = (ushort)u01;
          qk[(size_t)(row + 1) * 2048 + col] = (ushort)(u01 >> 16);
          qk[(size_t)(row + 2) * 2048 + col] = (ushort)u23;
          qk[(size_t)(row + 3) * 2048 + col] = (ushort)(u23 >> 16);
        }
      } else {  // V -> global V^T [b*1024 + (col-2048)][seq], 4 seq contiguous
        int dp = col - 2048;
#pragma unroll
        for (int ms = 0; ms < 4; ++ms) {
          int row = m0 + wm + ms * 16 + quad * 4;
          int b = row >> 11, seq = row & 2047;
          uint2 w = {cvt2bf(acc[ms][ns][0] + bv, acc[ms][ns][1] + bv),
                     cvt2bf(acc[ms][ns][2] + bv, acc[ms][ns][3] + bv)};
          *reinterpret_cast<uint2*>(
              &vtgout[((size_t)(b * 1024 + dp) << 11) + seq]) = w;
        }
      }
    }
  }
}

// --------------------------------------------------------------------------
// Flash attention, fixed-offset softmax, QG=2 q-tiles per block.
// Grid (bh=64, qg=16), 256 thr = 4 waves, 40960 B LDS -> 4 blocks/CU.
// --------------------------------------------------------------------------
#define QG 2  // q-tiles (of 64 rows) per block

__global__ __launch_bounds__(256, 4) void attn_kernel(
    const ushort* __restrict__ qk, const ushort* __restrict__ vtg,
    ushort* __restrict__ out) {
  __shared__ ushort Ks[2][4096];     // swizzled [key][d], double-buffered
  __shared__ ushort Vt[2][4096];     // swizzled [d][key], double-buffered
  __shared__ ushort Ps[4][16 * 64];  // per-wave [q][key], XOR-swizzled

  const int t = threadIdx.x;
  const int wave = t >> 6, lane = t & 63;
  const int lane15 = lane & 15, quad = lane >> 4;
  const int bh = blockIdx.x, qg = blockIdx.y;
  const int b = bh >> 4, h = bh & 15;
  const size_t boff = (size_t)b * SEQ * 2048;

  int sdst[2];
  const ushort* kptr[2];
  const ushort* vptr[2];
#pragma unroll
  for (int j = 0; j < 2; ++j) {
    int lg = (j * 4 + wave) * 64 + lane;
    int row = lg >> 3;
    int col = ((lg & 7) ^ (row & 7)) * 8;
    sdst[j] = (j * 4 + wave) * 512;
    kptr[j] = qk + boff + (size_t)row * 2048 + 1024 + h * 64 + col;
    vptr[j] = vtg + ((size_t)(b * 1024 + h * 64 + row) << 11) + col;
  }

  // Q fragments for QG q-tiles (B-operand for S^T = K*Q^T); pre-scaled
  bf16x8 qf[QG][2];
#pragma unroll
  for (int g = 0; g < QG; ++g) {
    size_t qoff = boff +
        (size_t)(qg * (QG * 64) + g * 64 + wave * 16 + lane15) * 2048 + h * 64;
    qf[g][0] = *reinterpret_cast<const bf16x8*>(&qk[qoff + quad * 8]);
    qf[g][1] = *reinterpret_cast<const bf16x8*>(&qk[qoff + 32 + quad * 8]);
  }

  bf16x8 ones;
#pragma unroll
  for (int j = 0; j < 8; ++j) ones[j] = (__bf16)1.0f;

  f32x4 O[QG][4] = {};  // rows q=quad*4+r, cols d=dsub*16+lane15
  f32x4 lacc[QG] = {};  // row-sums of P, broadcast over cols
  const int sw = lane15 & 7;
  ushort* ps = Ps[wave];

  // prologue: stage kt=0 into buffer 0
#pragma unroll
  for (int j = 0; j < 2; ++j) {
    gl2lds16(kptr[j], &Ks[0][sdst[j]]);
    gl2lds16(vptr[j], &Vt[0][sdst[j]]);
  }
  __syncthreads();

  for (int kt = 0; kt < SEQ / 64; ++kt) {
    const int cur = kt & 1, nxt = cur ^ 1;
    if (kt < SEQ / 64 - 1) {
#pragma unroll
      for (int j = 0; j < 2; ++j) {
        gl2lds16(kptr[j] + (size_t)(kt + 1) * 64 * 2048, &Ks[nxt][sdst[j]]);
        gl2lds16(vptr[j] + (kt + 1) * 64, &Vt[nxt][sdst[j]]);
      }
    }

    // hoisted K and V fragment reads, shared by the QG q-tiles
    bf16x8 kf[4][2], vf[2][4];
#pragma unroll
    for (int nsub = 0; nsub < 4; ++nsub) {
      const int kr = (nsub * 16 + lane15) * 64;
      kf[nsub][0] = *reinterpret_cast<const bf16x8*>(
          &Ks[cur][kr + ((quad ^ sw) * 8)]);
      kf[nsub][1] = *reinterpret_cast<const bf16x8*>(
          &Ks[cur][kr + (((quad + 4) ^ sw) * 8)]);
    }
#pragma unroll
    for (int kk = 0; kk < 2; ++kk)
#pragma unroll
      for (int dsub = 0; dsub < 4; ++dsub) {
        int d = dsub * 16 + lane15;
        vf[kk][dsub] = *reinterpret_cast<const bf16x8*>(
            &Vt[cur][d * 64 + (((kk * 4 + quad) ^ sw) * 8)]);
      }

#pragma unroll
    for (int g = 0; g < QG; ++g) {
      // S^T = K Q^T - 32 (fixed softmax offset in acc init)
      f32x4 st[4];
#pragma unroll
      for (int nsub = 0; nsub < 4; ++nsub) {
        f32x4 a = {-32.0f, -32.0f, -32.0f, -32.0f};
        a = mfma16(kf[nsub][0], qf[g][0], a);
        a = mfma16(kf[nsub][1], qf[g][1], a);
        st[nsub] = a;
      }
      // p = exp2(st) -> bf16 -> Ps row q=lane15; phys 16B block =
      // (2*nsub + (quad>>1)) ^ sw, half-block offset (quad&1)*4.
#pragma unroll
      for (int nsub = 0; nsub < 4; ++nsub) {
        uint2 w = {cvt2bf(fexp2(st[nsub][0]), fexp2(st[nsub][1])),
                   cvt2bf(fexp2(st[nsub][2]), fexp2(st[nsub][3]))};
        *reinterpret_cast<uint2*>(
            &ps[lane15 * 64 + (((2 * nsub + (quad >> 1)) ^ sw) << 3) +
                ((quad & 1) << 2)]) = w;
      }
      // O += P V ; lacc += P * ones. pf block = (kk*4+quad) ^ sw.
#pragma unroll
      for (int kk = 0; kk < 2; ++kk) {
        bf16x8 pf = *reinterpret_cast<const bf16x8*>(
            &ps[lane15 * 64 + (((kk * 4 + quad) ^ sw) << 3)]);
#pragma unroll
        for (int dsub = 0; dsub < 4; ++dsub)
          O[g][dsub] = mfma16(pf, vf[kk][dsub], O[g][dsub]);
        lacc[g] = mfma16(pf, ones, lacc[g]);
      }
    }
    __syncthreads();  // guards buffer swap; prefetch had a full kt to land
  }

  // Epilogue: normalize by l, store bf16
#pragma unroll
  for (int g = 0; g < QG; ++g)
#pragma unroll
    for (int r = 0; r < 4; ++r) {
      float linv = __builtin_amdgcn_rcpf(lacc[g][r]);
      size_t rowoff =
          (size_t)(b * SEQ + qg * (QG * 64) + g * 64 + wave * 16 + quad * 4 +
                   r) * EMBED + h * 64;
      uint u01 = cvt2bf(O[g][0][r] * linv, O[g][1][r] * linv);
      uint u23 = cvt2bf(O[g][2][r] * linv, O[g][3][r] * linv);
      out[rowoff + 0 * 16 + lane15] = (ushort)u01;
      out[rowoff + 1 * 16 + lane15] = (ushort)(u01 >> 16);
      out[rowoff + 2 * 16 + lane15] = (ushort)u23;
      out[rowoff + 3 * 16 + lane15] = (ushort)(u23 >> 16);
    }
}

// --------------------------------------------------------------------------
extern "C" void kernel_launch(void* const* d_in, const int* in_sizes, int n_in,
                              void* d_out, int out_size, void* d_ws,
                              size_t ws_size, hipStream_t stream) {
  const float* x = (const float*)d_in[0];
  const float* Wqkv = (const float*)d_in[1];
  const float* bqkv = (const float*)d_in[2];
  const float* Wproj = (const float*)d_in[3];
  const float* bproj = (const float*)d_in[4];
  float* out = (float*)d_out;

  char* ws = (char*)d_ws;
  // ws layout (75.5 MB):
  //   Wqkv_t  bf16 [3072][1024]        6 MB   @ 0
  //   Wproj_t bf16 [1024][1024]        2 MB   @ 6291456
  //   qk      bf16 [8192][2048]       32 MB   @ 8388608
  //   vtg     bf16 [4][16][64][2048]  16 MB   @ 41943040
  //   xb / attnout (aliased) bf16     16 MB   @ 58720256
  ushort* Wqkv_t = (ushort*)ws;
  ushort* Wproj_t = (ushort*)(ws + 6291456);
  ushort* qk = (ushort*)(ws + 8388608);
  ushort* vtg = (ushort*)(ws + 41943040);
  ushort* xb = (ushort*)(ws + 58720256);
  ushort* attnout = (ushort*)(ws + 58720256);  // alias: xb dead after QKV GEMM

  prep_kernel<<<8192 + 768 + 256, 256, 0, stream>>>(
      x, xb, Wqkv, Wqkv_t, Wproj, Wproj_t);
  gemm_bf16<<<dim3(QKV_N / 128, M_TOT / 128), 512, 0, stream>>>(
      xb, Wqkv_t, bqkv, qk, vtg, M_TOT, QKV_N, EMBED, 1);
  attn_kernel<<<dim3(NHEAD * BATCH, SEQ / (QG * 64)), 256, 0, stream>>>(
      qk, vtg, attnout);
  gemm_bf16<<<dim3(EMBED / 128, M_TOT / 128), 512, 0, stream>>>(
      attnout, Wproj_t, bproj, out, nullptr, M_TOT, EMBED, EMBED, 0);
}